// Round 1
// baseline (300.106 us; speedup 1.0000x reference)
//
#include <hip/hip_runtime.h>

// Problem constants (match reference)
#define RREL 8
#define COUT 4
#define NEDGE 2000000
#define E4   (NEDGE / 4)      // 500,000 float4 per relation
#define N4   (RREL * E4)      // 4,000,000 float4 total in edge_w
#define BLOCK 256
#define GRID  (N4 / BLOCK)    // 15625, exact — no tail check needed

typedef float vfloat4 __attribute__((ext_vector_type(4)));

// ---------------------------------------------------------------------------
// Fused kernel: every block redundantly computes the 4x8 softmax from
// `weight` (128 B, L2-broadcast — cheap), then scales its slice of edge_w
// into the 4 output channels. Block 0 also writes the Filter tuple output.
// One thread per float4 of edge_w: 1 plain 16B load, 4 plain 16B stores.
//
// R1 change vs R0: removed ALL __builtin_nontemporal_* hints. The harness's
// own fillBuffer dispatches prove plain full-line stores run at 6.4 TB/s
// with FETCH_SIZE ~ 0 (no RFO on full-line L2 allocation), so the `nt`
// flag has no upside here and is the prime suspect for the kernel running
// at ~2.4 TB/s instead of ~6 TB/s.
// ---------------------------------------------------------------------------
__global__ void __launch_bounds__(BLOCK)
gtconv_fused_kernel(const vfloat4* __restrict__ ew4,
                    const float* __restrict__ weight,   // [C, R]
                    vfloat4* __restrict__ out4,         // [C, R*E/4]
                    float* __restrict__ filter_out) {   // [C, R] tuple elem 1
    __shared__ float sf[COUT * RREL];

    int t = threadIdx.x;
    if (t < COUT) {
        // Thread t computes softmax row t (8 elements) serially.
        float v[RREL];
        float m = -3.402823e38f;
        #pragma unroll
        for (int r = 0; r < RREL; ++r) {
            v[r] = weight[t * RREL + r];
            m = fmaxf(m, v[r]);
        }
        float s = 0.0f;
        #pragma unroll
        for (int r = 0; r < RREL; ++r) {
            v[r] = __expf(v[r] - m);
            s += v[r];
        }
        float inv = 1.0f / s;
        #pragma unroll
        for (int r = 0; r < RREL; ++r) {
            float f = v[r] * inv;
            sf[t * RREL + r] = f;
            if (blockIdx.x == 0) filter_out[t * RREL + r] = f;
        }
    }
    __syncthreads();

    int idx = blockIdx.x * BLOCK + t;     // < N4 exactly, no tail
    int r = idx / E4;                     // relation index (magic-mul)

    vfloat4 w = ew4[idx];

    #pragma unroll
    for (int c = 0; c < COUT; ++c) {
        float f = sf[c * RREL + r];
        vfloat4 o = w * f;
        out4[(size_t)c * N4 + idx] = o;
    }
}

extern "C" void kernel_launch(void* const* d_in, const int* in_sizes, int n_in,
                              void* d_out, int out_size, void* d_ws, size_t ws_size,
                              hipStream_t stream) {
    const float* edge_w = (const float*)d_in[0];   // [R, E] f32
    const float* weight = (const float*)d_in[1];   // [C, R] f32
    float* out = (float*)d_out;                    // [C*R*E] out ++ [C*R] Filter

    float* filter_slot = out + (size_t)COUT * RREL * NEDGE;

    gtconv_fused_kernel<<<GRID, BLOCK, 0, stream>>>(
        (const vfloat4*)edge_w, weight, (vfloat4*)out, filter_slot);
}